// Round 10
// baseline (177.410 us; speedup 1.0000x reference)
//
#include <hip/hip_runtime.h>
#include <cstdint>
#include <cstddef>

#define NP  1024
#define FD  10
#define BSZ 128
#define TPB 512   // 8 waves; each wave owns 128 rows (4 row-tiles of 32)
#define NW  8
#define RT  4     // row-tiles per wave

// One block per (pair, dir): bid = pair*2 + d.
//   d=0: rows = state(ag), cols = goal(dg)   (reward_s2g)
//   d=1: rows = goal(dg),  cols = state(ag)  (reward_g2s)
//
// R10 = R9 LDS half-planes + 4-CONCURRENT MFMA chains + R4 tile tracking and
// R4's 32-col global-rescan epilogue.
// Rationale: R4-R9 pinned at ~108-110us with MfmaUtil ~27% and active waves
// ~12/CU (register-capped at 4 waves/SIMD by the unified VGPR+AGPR file).
// Since occupancy cannot rise, raise per-wave matrix-pipe density: issue all
// 4 rt-chains' mfma1s back-to-back, then the 4 chained mfma2s. Chain-local
// sequences are unchanged -> bit-identical acc values (issue order only).
// Budget: 4 live f32x16 accs (+32 regs) paid by tile tracking (-24) vs quad.
// d(n,m) = cs_m - 2 r_n . c_m via bf16 split-3 limbs in K=32 (two chained
// 32x32x16 bf16 MFMAs). Terms (absmax 0.0 x8): ChRh, CmRh, ClRh, ChRm,
// CmRm, ChRl, CmRl + cs split-3 (drops only ClRm/ClRl <= 2^-24 rel).
// LDS half-planes (32 KB): Ch, Cm, Cl, cs3. A-fragments per k-half:
//   a1 = [Ch | Cm]                      (B: Rh k-half0, Rm k-half1)
//   a2 = hh ? [Cm | cs3] : [Cl | Ch]    (B: h0 (Rh,Rl), h1 (Rl, 1,1,1,0))
// Pass 1 tracks (min, ct) per TILE (R4-validated): 8-op min3 tree + strict <
// keeps FIRST ct; shfl_xor(32) lexicographic merge completes the tile;
// publish (ct, thr) per row to LDS scratch. Epilogue (R4 verbatim): per row,
// fp32 rescan of the winning tile's 32 cols from GLOBAL (bit-identical
// staging-chain recompute; ascending j + strict < = reference first-index
// argmin), winner xy, threshold.
typedef __attribute__((ext_vector_type(8)))  __bf16 bf16x8;
typedef __attribute__((ext_vector_type(16))) float  f32x16;

__device__ inline unsigned int pk2(__bf16 a, __bf16 b) {
    union { __bf16 h; unsigned short u; } ua, ub;
    ua.h = a; ub.h = b;
    return (unsigned int)ua.u | ((unsigned int)ub.u << 16);
}

__device__ inline void split3(float x, __bf16& h, __bf16& m, __bf16& l) {
    h = (__bf16)x;
    float r1 = x - (float)h;    // exact (h carries x's exponent, 8-bit mantissa)
    m = (__bf16)r1;
    float r2 = r1 - (float)m;   // exact
    l = (__bf16)r2;
}

__device__ inline float min3f(float a, float b, float c) {
    return fminf(fminf(a, b), c);   // fuses to v_min3_f32; order-invariant exact
}

extern "C" __global__ __launch_bounds__(TPB, 4)   // VGPR cap 128; 4 waves/SIMD band
void chamfer_pairs(const float* __restrict__ ag, const float* __restrict__ dg,
                   const float* __restrict__ nmean, const float* __restrict__ nstd,
                   float* __restrict__ out /* [BSZ], pre-zeroed */)
{
    // Four 8-byte half-planes: Ch, Cm, Cl, cs -> 4 x 8KB = 32 KB.
    __shared__ __align__(16) unsigned int ldsH[4 * NP * 2];
    __shared__ float red[NW];

    const int bid  = blockIdx.x;        // 0..1023
    const int pair = bid >> 1;
    const int d    = bid & 1;
    const int tid  = threadIdx.x;
    const int wv   = tid >> 6;          // wave 0..7
    const int l    = tid & 63;
    const int ln   = l & 31;            // lane's row slot / col slot
    const int hh   = l >> 5;            // k-half owner

    const float* rowsrc = ((d == 0) ? ag : dg) + (size_t)pair * (NP * FD);
    const float* colsrc = ((d == 0) ? dg : ag) + (size_t)pair * (NP * FD);

    // -2*(std, mean) for vis features 5..8 (uniform -> scalar regs).
    const float s5 = -2.0f * nstd[5], m5 = -2.0f * nmean[5];
    const float s6 = -2.0f * nstd[6], m6 = -2.0f * nmean[6];
    const float s7 = -2.0f * nstd[7], m7 = -2.0f * nmean[7];
    const float s8 = -2.0f * nstd[8], m8 = -2.0f * nmean[8];
    const float std0 = nstd[0], mean0 = nmean[0];
    const float std1 = nstd[1], mean1 = nmean[1];

    // ---- Stage columns: C = t = fmaf(raw,-2s,-2m) (= -2c, proven chain),
    //      cs = 0.25*dot(t,t); split-3 into the 4 half-planes.
    for (int m = tid; m < NP; m += TPB) {
        const float* p = colsrc + (size_t)m * FD;
        float t0 = fmaf(p[5], s5, m5);
        float t1 = fmaf(p[6], s6, m6);
        float t2 = fmaf(p[7], s7, m7);
        float t3 = fmaf(p[8], s8, m8);
        float cs = 0.25f * (t0 * t0 + t1 * t1 + t2 * t2 + t3 * t3);
        __bf16 ch0, cm0, cl0, ch1, cm1, cl1, ch2, cm2, cl2, ch3, cm3, cl3;
        __bf16 qh, qm, ql;
        split3(t0, ch0, cm0, cl0);
        split3(t1, ch1, cm1, cl1);
        split3(t2, ch2, cm2, cl2);
        split3(t3, ch3, cm3, cl3);
        split3(cs, qh, qm, ql);
        const __bf16 z = (__bf16)0.0f;
        uint2* ph = (uint2*)ldsH;
        ph[0 * NP + m] = make_uint2(pk2(ch0, ch1), pk2(ch2, ch3));   // Ch
        ph[1 * NP + m] = make_uint2(pk2(cm0, cm1), pk2(cm2, cm3));   // Cm
        ph[2 * NP + m] = make_uint2(pk2(cl0, cl1), pk2(cl2, cl3));   // Cl
        ph[3 * NP + m] = make_uint2(pk2(qh, qm),   pk2(ql, z));      // cs3
    }

    // ---- Rows: split-3 of r = -0.5*t (proven lineage); B fragments per
    //      k-half; threshold rthr = 6 - 0.25*dot(t,t).
    bf16x8 B1[RT], B2[RT];
    float  rthr[RT];
    const __bf16 kone = (__bf16)1.0f;
    const __bf16 kzb  = (__bf16)0.0f;
#pragma unroll
    for (int rt = 0; rt < RT; ++rt) {
        int n = wv * 128 + rt * 32 + ln;
        const float* p = rowsrc + (size_t)n * FD;
        float t0 = fmaf(p[5], s5, m5);
        float t1 = fmaf(p[6], s6, m6);
        float t2 = fmaf(p[7], s7, m7);
        float t3 = fmaf(p[8], s8, m8);
        float rss = 0.25f * (t0 * t0 + t1 * t1 + t2 * t2 + t3 * t3);
        rthr[rt] = 6.0f - rss;
        float r0 = -0.5f * t0, r1 = -0.5f * t1, r2 = -0.5f * t2, r3 = -0.5f * t3;
        __bf16 rh0, rm0, rl0, rh1, rm1, rl1, rh2, rm2, rl2, rh3, rm3, rl3;
        split3(r0, rh0, rm0, rl0);
        split3(r1, rh1, rm1, rl1);
        split3(r2, rh2, rm2, rl2);
        split3(r3, rh3, rm3, rl3);
        // MFMA1: K0-7 = Ch.Rh, Cm.Rh ; K8-15 = Ch.Rm, Cm.Rm  (A = [Ch|Cm] both halves)
        __bf16 p0 = hh ? rm0 : rh0;
        __bf16 p1 = hh ? rm1 : rh1;
        __bf16 p2 = hh ? rm2 : rh2;
        __bf16 p3 = hh ? rm3 : rh3;
        bf16x8 b1;
        b1[0] = p0; b1[1] = p1; b1[2] = p2; b1[3] = p3;
        b1[4] = p0; b1[5] = p1; b1[6] = p2; b1[7] = p3;
        // MFMA2: K0-7 = Cl.Rh, Ch.Rl (A=[Cl|Ch]) ; K8-15 = Cm.Rl, cs*1 (A=[Cm|cs3])
        __bf16 q0 = hh ? rl0 : rh0;
        __bf16 q1 = hh ? rl1 : rh1;
        __bf16 q2 = hh ? rl2 : rh2;
        __bf16 q3 = hh ? rl3 : rh3;
        bf16x8 b2;
        b2[0] = q0; b2[1] = q1; b2[2] = q2; b2[3] = q3;
        b2[4] = hh ? kone : rl0;
        b2[5] = hh ? kone : rl1;
        b2[6] = hh ? kone : rl2;
        b2[7] = hh ? kzb  : rl3;
        B1[rt] = b1; B2[rt] = b2;
    }
    __syncthreads();

    // ---- Pass 1: 32 col-tiles; per ct: 4 ds_read_b64 assemble a1/a2, then
    //      4 INDEPENDENT mfma1s back-to-back, then the 4 chained mfma2s
    //      (dense matrix-pipe groups, cross-chain latency hiding; chain-local
    //      order unchanged -> bit-identical), then R4 tile tracking.
    f32x16 kz = {0.0f,0.0f,0.0f,0.0f,0.0f,0.0f,0.0f,0.0f,
                 0.0f,0.0f,0.0f,0.0f,0.0f,0.0f,0.0f,0.0f};
    float runmin[RT];
    int   runct[RT];
#pragma unroll
    for (int rt = 0; rt < RT; ++rt) { runmin[rt] = 3.0e38f; runct[rt] = 0; }

    const size_t lnoff = (size_t)ln * 8;
    const char* bCh = (const char*)ldsH + 0 * (NP * 8) + lnoff;
    const char* bCm = (const char*)ldsH + 1 * (NP * 8) + lnoff;
    const char* bCl = (const char*)ldsH + 2 * (NP * 8) + lnoff;
    const char* bCs = (const char*)ldsH + 3 * (NP * 8) + lnoff;
    const char* bLo2 = hh ? bCm : bCl;   // a2 low  half source (hh-uniform ptr)
    const char* bHi2 = hh ? bCs : bCh;   // a2 high half source

#define TRACK(RT_, A_)                                                        \
    {                                                                         \
        float u0 = min3f(A_[0],  A_[1],  A_[2]);                              \
        float u1 = min3f(A_[3],  A_[4],  A_[5]);                              \
        float u2 = min3f(A_[6],  A_[7],  A_[8]);                              \
        float u3 = min3f(A_[9],  A_[10], A_[11]);                             \
        float u4 = min3f(A_[12], A_[13], A_[14]);                             \
        float mn = fminf(min3f(u0, u1, u2), min3f(u3, u4, A_[15]));           \
        bool lt = mn < runmin[RT_];          /* strict < keeps FIRST ct */    \
        runmin[RT_] = fminf(runmin[RT_], mn);                                 \
        runct[RT_]  = lt ? ct : runct[RT_];                                   \
    }

    for (int ct = 0; ct < 32; ++ct) {
        const size_t off = (size_t)ct * 256;   // 32 cols x 8 B per half-plane
        bf16x8 a1, a2;
        *((uint2*)&a1)     = *(const uint2*)(bCh + off);
        *((uint2*)&a1 + 1) = *(const uint2*)(bCm + off);
        *((uint2*)&a2)     = *(const uint2*)(bLo2 + off);
        *((uint2*)&a2 + 1) = *(const uint2*)(bHi2 + off);
        f32x16 ac0 = __builtin_amdgcn_mfma_f32_32x32x16_bf16(a1, B1[0], kz, 0, 0, 0);
        f32x16 ac1 = __builtin_amdgcn_mfma_f32_32x32x16_bf16(a1, B1[1], kz, 0, 0, 0);
        f32x16 ac2 = __builtin_amdgcn_mfma_f32_32x32x16_bf16(a1, B1[2], kz, 0, 0, 0);
        f32x16 ac3 = __builtin_amdgcn_mfma_f32_32x32x16_bf16(a1, B1[3], kz, 0, 0, 0);
        ac0 = __builtin_amdgcn_mfma_f32_32x32x16_bf16(a2, B2[0], ac0, 0, 0, 0);
        ac1 = __builtin_amdgcn_mfma_f32_32x32x16_bf16(a2, B2[1], ac1, 0, 0, 0);
        ac2 = __builtin_amdgcn_mfma_f32_32x32x16_bf16(a2, B2[2], ac2, 0, 0, 0);
        ac3 = __builtin_amdgcn_mfma_f32_32x32x16_bf16(a2, B2[3], ac3, 0, 0, 0);
        TRACK(0, ac0)
        TRACK(1, ac1)
        TRACK(2, ac2)
        TRACK(3, ac3)
    }
#undef TRACK
    __syncthreads();   // all half-plane reads done; ldsH reusable as scratch

    // ---- Merge k-halves (lane covers the hh-interleaved 16 of each tile's
    //      32 cols): shfl_xor(32) lexicographic (val, ct); publish (ct, thr)
    //      per row to LDS scratch (R4 structure).
    int*   sCt  = (int*)ldsH;            // [1024]
    float* sThr = (float*)ldsH + NP;     // [1024]
#pragma unroll
    for (int rt = 0; rt < RT; ++rt) {
        float bv = runmin[rt];
        int   bc = runct[rt];
        float ov = __shfl_xor(bv, 32);
        int   oc = __shfl_xor(bc, 32);
        bool take = (ov < bv) || (ov == bv && oc < bc);
        bv = take ? ov : bv;
        bc = take ? oc : bc;
        if (hh == 0) {
            int n = wv * 128 + rt * 32 + ln;
            sCt[n]  = bc;
            sThr[n] = rthr[rt];
        }
    }
    __syncthreads();

    // ---- Epilogue (R4 verbatim): per row, fp32 re-scan of the winning
    //      32-col tile from GLOBAL with the proven fmaf chain; first-index
    //      argmin (strict <), xy gather, threshold.
    float sum = 0.0f;
    for (int q = 0; q < 2; ++q) {
        int n = tid * 2 + q;
        int ct = sCt[n];
        float thr = sThr[n];
        const float* pr = rowsrc + (size_t)n * FD;
        float t0 = fmaf(pr[5], s5, m5);
        float t1 = fmaf(pr[6], s6, m6);
        float t2 = fmaf(pr[7], s7, m7);
        float t3 = fmaf(pr[8], s8, m8);
        float vx = -0.5f * t0, vy = -0.5f * t1, vz = -0.5f * t2, vw = -0.5f * t3;
        float best = 3.0e38f;
        int bidx = 0;
        const int mbase = ct * 32;
#pragma unroll 4
        for (int j = 0; j < 32; ++j) {
            const float* pc = colsrc + (size_t)(mbase + j) * FD;
            float c0 = fmaf(pc[5], s5, m5);
            float c1 = fmaf(pc[6], s6, m6);
            float c2 = fmaf(pc[7], s7, m7);
            float c3 = fmaf(pc[8], s8, m8);
            float cs = 0.25f * (c0 * c0 + c1 * c1 + c2 * c2 + c3 * c3);
            float dd = fmaf(vx, c0, cs);
            dd = fmaf(vy, c1, dd);
            dd = fmaf(vz, c2, dd);
            dd = fmaf(vw, c3, dd);
            if (dd < best) { best = dd; bidx = mbase + j; }  // first idx on ties
        }
        const float* pw = colsrc + (size_t)bidx * FD;
        float gx = fmaf(pw[0], std0, mean0);
        float gy = fmaf(pw[1], std1, mean1);
        float ax = fmaf(pr[0], std0, mean0);
        float ay = fmaf(pr[1], std1, mean1);
        float dx = ax - gx;
        float dy = ay - gy;
        float dist = sqrtf(dx * dx + dy * dy);
        if (best > thr) dist = 1.0f;     // min_d > LATENT_DIST_THRESHOLD
        sum += dist;
    }

    // ---- Reduce: wave shuffle, cross-wave LDS, one atomic per block.
    for (int o = 32; o > 0; o >>= 1) sum += __shfl_down(sum, o, 64);
    if ((tid & 63) == 0) red[tid >> 6] = sum;
    __syncthreads();
    if (tid == 0) {
        float s = red[0] + red[1] + red[2] + red[3]
                + red[4] + red[5] + red[6] + red[7];
        // out[b] = -(sum over 4 views x 2 dirs x 1024 rows) / 8192
        atomicAdd(&out[bid >> 3], s * (-1.0f / 8192.0f));
    }
}

extern "C" void kernel_launch(void* const* d_in, const int* in_sizes, int n_in,
                              void* d_out, int out_size, void* d_ws, size_t ws_size,
                              hipStream_t stream)
{
    const float* ag = (const float*)d_in[0];   // achieved_goal (128,4,1024,10)
    const float* dg = (const float*)d_in[1];   // desired_goal  (128,4,1024,10)
    const float* nm = (const float*)d_in[2];   // norm_mean (10,)
    const float* ns = (const float*)d_in[3];   // norm_std  (10,)

    hipMemsetAsync(d_out, 0, BSZ * sizeof(float), stream);   // out is accumulated
    chamfer_pairs<<<BSZ * 4 * 2, TPB, 0, stream>>>(ag, dg, nm, ns, (float*)d_out);
}